// Round 8
// baseline (56142.627 us; speedup 1.0000x reference)
//
#include <hip/hip_runtime.h>
#include <stdint.h>

#define HH 4096
#define WW 4096
#define NPIX (HH * WW)
#define NBINS 8192
#define NFRAG 64
#define FRAG_PIX (512 * 512)   // 2^18
#define WPR 64                 // u64 words per row (4096/64)
#define NWORDS (HH * WPR)      // 262144

// stop conditions, proven exactly equivalent to both f32 and f64 reference
// comparisons:  frac<0.12 stops at cnt>=31458 ; frac>0.08 stops at cnt<=20971
#define STOP_HI 31458
#define STOP_LO 20971

__device__ __forceinline__ int frag_of(int py, int px) {
  return ((py >> 9) << 3) + (px >> 9);
}

__device__ __forceinline__ int bin_of(float v) {
  int b = (int)(v * 8192.0f);   // monotone f32 map
  if (b < 0) b = 0;
  if (b > NBINS - 1) b = NBINS - 1;
  return b;
}

// ---------------------------------------------------------------------------
// 1) 5x5 box blur, SAME zero padding.
//    Chain hypothesis H-A (numpy port: sliding_window_view -> materialized
//    (windows*k) temp -> .sum((-2,-1)) over a CONTIGUOUS 25-float axis ->
//    numpy pairwise_sum_FLOAT, n=25 branch):
//      p[i] = f32(x_i * K), row-major i=(dy+2)*5+(dx+2), OOB -> exact 0.0
//      r[j] = (p[j] + p[j+8]) + p[j+16]          (j = 0..7)
//      res  = ((r0+r1)+(r2+r3)) + ((r4+r5)+(r6+r7))
//      res += p[24]
//    Zero taps are exact no-ops at every node, so zero-filling OOB taps
//    reproduces the padded computation bit-exactly. No FMA anywhere
//    (__fmul_rn/__fadd_rn are never contracted).
// ---------------------------------------------------------------------------
__global__ void blur_kernel(const float* __restrict__ x, float* __restrict__ out) {
  int idx = blockIdx.x * blockDim.x + threadIdx.x;
  int px = idx & (WW - 1);
  int py = idx >> 12;
  const float K = (float)(1.0 / 25.0);
  float p[25];
#pragma unroll
  for (int i = 0; i < 25; ++i) {
    int dy = i / 5 - 2;
    int dx = i % 5 - 2;
    int yy = py + dy;
    int xx = px + dx;
    float v = 0.0f;
    if ((unsigned)yy < (unsigned)HH && (unsigned)xx < (unsigned)WW) {
      v = x[yy * WW + xx];
    }
    p[i] = __fmul_rn(v, K);
  }
  float r0 = __fadd_rn(__fadd_rn(p[0], p[8]),  p[16]);
  float r1 = __fadd_rn(__fadd_rn(p[1], p[9]),  p[17]);
  float r2 = __fadd_rn(__fadd_rn(p[2], p[10]), p[18]);
  float r3 = __fadd_rn(__fadd_rn(p[3], p[11]), p[19]);
  float r4 = __fadd_rn(__fadd_rn(p[4], p[12]), p[20]);
  float r5 = __fadd_rn(__fadd_rn(p[5], p[13]), p[21]);
  float r6 = __fadd_rn(__fadd_rn(p[6], p[14]), p[22]);
  float r7 = __fadd_rn(__fadd_rn(p[7], p[15]), p[23]);
  float res = __fadd_rn(
      __fadd_rn(__fadd_rn(r0, r1), __fadd_rn(r2, r3)),
      __fadd_rn(__fadd_rn(r4, r5), __fadd_rn(r6, r7)));
  res = __fadd_rn(res, p[24]);
  out[idx] = res;
}

// ---------------------------------------------------------------------------
// 2a) per-fragment histogram (8192 bins)
// ---------------------------------------------------------------------------
__global__ void hist_kernel(const float* __restrict__ blur, uint32_t* __restrict__ hist) {
  int idx = blockIdx.x * blockDim.x + threadIdx.x;
  float v = blur[idx];
  int f = frag_of(idx >> 12, idx & (WW - 1));
  atomicAdd(&hist[f * NBINS + bin_of(v)], 1u);
}

// ---------------------------------------------------------------------------
// 2b) per-fragment exclusive prefix -> P[f][0..8192]
// ---------------------------------------------------------------------------
__global__ void prefix_kernel(const uint32_t* __restrict__ hist, uint32_t* __restrict__ P) {
  int f = blockIdx.x;
  int tid = threadIdx.x;  // 256 threads, 32 bins each
  const uint32_t* hf = hist + f * NBINS;
  uint32_t* Pf = P + f * (NBINS + 1);
  __shared__ uint32_t segsum[256];
  __shared__ uint32_t segoff[256];
  int base = tid * 32;
  uint32_t s = 0;
  for (int i = 0; i < 32; ++i) s += hf[base + i];
  segsum[tid] = s;
  __syncthreads();
  if (tid == 0) {
    uint32_t a = 0;
    for (int i = 0; i < 256; ++i) { segoff[i] = a; a += segsum[i]; }
  }
  __syncthreads();
  uint32_t off = segoff[tid];
  for (int i = 0; i < 32; ++i) {
    Pf[base + i] = off;
    off += hf[base + i];
  }
  if (tid == 255) Pf[NBINS] = off;   // == FRAG_PIX
}

// ---------------------------------------------------------------------------
// 3) threshold walk, one 256-thread block. Per 64-rung batch: exact f32
//    ladder in s_tab (ascending), scan fragment, classify band pixels into
//    c = #{rungs < v} (guess + exact fixup), histogram c, suffix-sum ->
//    exact counts for all 64 rungs; ballot picks the while-loop exit.
// ---------------------------------------------------------------------------
__global__ void walk_kernel(const float* __restrict__ blur,
                            const uint32_t* __restrict__ P,
                            float* __restrict__ th_out) {
  __shared__ float s_tab[64];
  __shared__ uint32_t c_hist[65];
  __shared__ float th_sh;
  __shared__ int done_sh;
  __shared__ int b0_sh, b63_sh;
  __shared__ uint32_t base_sh;
  int tid = threadIdx.x;
  if (tid == 0) th_sh = 0.5f;   // TH1_INIT
  __syncthreads();
  for (int f = 0; f < NFRAG; ++f) {
    const uint32_t* Pf = P + f * (NBINS + 1);
    int fi = f >> 3, fj = f & 7;
    const float* frag0 = blur + fi * 512 * WW + fj * 512;
    for (int phase = 0; phase < 2; ++phase) {
      if (tid == 0) done_sh = 0;
      __syncthreads();
      for (;;) {
        if (tid < 64) {
          float r = th_sh;
          if (phase == 0) { for (int i = 0; i < tid; ++i) r = __fadd_rn(r, -0.0005f); }
          else            { for (int i = 0; i < tid; ++i) r = __fadd_rn(r,  0.0005f); }
          s_tab[(phase == 0) ? (63 - tid) : tid] = r;   // ascending order
        }
        if (tid < 65) c_hist[tid] = 0;
        __syncthreads();
        if (tid == 0) {
          b0_sh = bin_of(s_tab[0]);
          b63_sh = bin_of(s_tab[63]);
          base_sh = FRAG_PIX - Pf[b63_sh + 1];   // pixels in bins strictly above band
        }
        __syncthreads();
        int b0 = b0_sh, b63 = b63_sh;
        float s0 = s_tab[0];
        for (int it = tid; it < 512 * 128; it += 256) {
          int rr = it >> 7, c4 = it & 127;
          const float4 v4 = *(const float4*)(frag0 + rr * WW + c4 * 4);
          float vv[4] = {v4.x, v4.y, v4.z, v4.w};
#pragma unroll
          for (int e = 0; e < 4; ++e) {
            float v = vv[e];
            int b = bin_of(v);
            if (b >= b0 && b <= b63) {
              int c = (int)((v - s0) * 2000.0f);
              if (c < 0) c = 0;
              if (c > 64) c = 64;
              while (c < 64 && s_tab[c] < v) ++c;        // exact fixup
              while (c > 0 && s_tab[c - 1] >= v) --c;
              atomicAdd(&c_hist[c], 1u);                  // c = #{rungs < v}
            }
          }
        }
        __syncthreads();
        if (tid < 64) {
          int k = (phase == 0) ? (63 - tid) : tid;        // s-index of rung tid
          uint32_t cnt = base_sh;
          for (int i = k + 1; i <= 64; ++i) cnt += c_hist[i];  // #{v > s_k}
          float r = s_tab[k];
          bool stop = (phase == 0) ? (cnt >= STOP_HI) : (cnt <= STOP_LO);
          unsigned long long bal = __ballot(stop);
          if (bal) {
            int src = __ffsll(bal) - 1;                   // first while-iter that stops
            float chosen = __shfl(r, src);
            if (tid == 0) { th_sh = chosen; done_sh = 1; }
          } else {
            float r63 = __shfl(r, 63);
            if (tid == 0) th_sh = __fadd_rn(r63, (phase == 0) ? -0.0005f : 0.0005f);
          }
        }
        __syncthreads();
        if (done_sh) break;
      }
    }
    if (tid == 0) th_out[f] = th_sh;
    __syncthreads();
  }
}

// ---------------------------------------------------------------------------
// 4) mask + bit-pack via wave ballot (64 consecutive px per u64 word)
// ---------------------------------------------------------------------------
__global__ void mask_pack_kernel(const float* __restrict__ blur,
                                 const float* __restrict__ th,
                                 unsigned long long* __restrict__ pk) {
  int idx = blockIdx.x * blockDim.x + threadIdx.x;
  int px = idx & (WW - 1);
  int py = idx >> 12;
  bool on = blur[idx] > th[frag_of(py, px)];
  unsigned long long w = __ballot(on);
  if ((threadIdx.x & 63) == 0) pk[idx >> 6] = w;
}

// ---------------------------------------------------------------------------
// 5) packed 5x5 morphology. Dilate = vmax(hmax(.)) with OOB=0.
//    Erode = ~dilate(~x) (De Morgan handles the clipped window exactly).
// ---------------------------------------------------------------------------
template <bool COMP>
__global__ void hmax_kernel(const unsigned long long* __restrict__ in,
                            unsigned long long* __restrict__ out) {
  int w = blockIdx.x * blockDim.x + threadIdx.x;
  if (w >= NWORDS) return;
  int wx = w & (WPR - 1);
  unsigned long long m = COMP ? ~in[w] : in[w];
  unsigned long long l = (wx > 0) ? (COMP ? ~in[w - 1] : in[w - 1]) : 0ull;
  unsigned long long r = (wx < WPR - 1) ? (COMP ? ~in[w + 1] : in[w + 1]) : 0ull;
  out[w] = m | (m << 1) | (m << 2) | (m >> 1) | (m >> 2)
             | (l >> 62) | (l >> 63) | (r << 62) | (r << 63);
}

__global__ void vmax_kernel(const unsigned long long* __restrict__ in,
                            unsigned long long* __restrict__ out) {
  int w = blockIdx.x * blockDim.x + threadIdx.x;
  if (w >= NWORDS) return;
  int wy = w >> 6;
  int wx = w & (WPR - 1);
  unsigned long long res = 0ull;
#pragma unroll
  for (int d = -2; d <= 2; ++d) {
    int yy = wy + d;
    if ((unsigned)yy < (unsigned)HH) res |= in[yy * WPR + wx];
  }
  out[w] = res;
}

// final unpack; folds the trailing complement of the erode De Morgan pair
__global__ void unpack_kernel(const unsigned long long* __restrict__ in,
                              float* __restrict__ out) {
  int idx = blockIdx.x * blockDim.x + threadIdx.x;
  unsigned long long w = in[idx >> 6];
  int bit = (int)((w >> (idx & 63)) & 1ull);
  out[idx] = (float)(1 - bit);
}

// ---------------------------------------------------------------------------
extern "C" void kernel_launch(void* const* d_in, const int* in_sizes, int n_in,
                              void* d_out, int out_size, void* d_ws, size_t ws_size,
                              hipStream_t stream) {
  const float* x = (const float*)d_in[0];
  if (n_in > 1 && in_sizes[0] != NPIX) x = (const float*)d_in[1];
  float* out = (float*)d_out;
  char* ws = (char*)d_ws;

  // workspace layout — TOTAL 8.4 MB
  const size_t OFF_HIST = 0;          // 64*8192*4   = 2,097,152
  const size_t OFF_P    = 2097152;    // 64*8193*4   = 2,097,408
  const size_t OFF_TH   = 4194560;    // 256
  const size_t OFF_PKA  = 4194816;    // 262144*8    = 2,097,152
  const size_t OFF_PKB  = 6291968;    // 262144*8    = 2,097,152  (end 8,389,120)
  uint32_t* hist = (uint32_t*)(ws + OFF_HIST);
  uint32_t* P    = (uint32_t*)(ws + OFF_P);
  float*    th   = (float*)(ws + OFF_TH);
  unsigned long long* PKA = (unsigned long long*)(ws + OFF_PKA);
  unsigned long long* PKB = (unsigned long long*)(ws + OFF_PKB);

  float* blurred = out;   // blur lives in d_out; unpack rewrites it at the end

  const int TPB = 256;
  const int NB = NPIX / TPB;       // 65536
  const int NBW = NWORDS / TPB;    // 1024

  blur_kernel<<<NB, TPB, 0, stream>>>(x, blurred);
  hipMemsetAsync(hist, 0, (size_t)NFRAG * NBINS * sizeof(uint32_t), stream);
  hist_kernel<<<NB, TPB, 0, stream>>>(blurred, hist);
  prefix_kernel<<<NFRAG, 256, 0, stream>>>(hist, P);
  walk_kernel<<<1, 256, 0, stream>>>(blurred, P, th);
  mask_pack_kernel<<<NB, TPB, 0, stream>>>(blurred, th, PKA);
  hmax_kernel<false><<<NBW, TPB, 0, stream>>>(PKA, PKB);  // dilate H
  vmax_kernel<<<NBW, TPB, 0, stream>>>(PKB, PKA);         // dilate V
  hmax_kernel<true><<<NBW, TPB, 0, stream>>>(PKA, PKB);   // erode H (complement in)
  vmax_kernel<<<NBW, TPB, 0, stream>>>(PKB, PKA);         // erode V
  unpack_kernel<<<NB, TPB, 0, stream>>>(PKA, out);        // out = ~bit
}

// Round 9
// 2241.492 us; speedup vs baseline: 25.0470x; 25.0470x over previous
//
#include <hip/hip_runtime.h>
#include <stdint.h>

#define HH 4096
#define WW 4096
#define NPIX (HH * WW)
#define NBINS 8192
#define NFRAG 64
#define FRAG_PIX (512 * 512)   // 2^18
#define WPR 64                 // u64 words per row (4096/64)
#define NWORDS (HH * WPR)      // 262144
#define CAP 4096               // per-fragment critical-band capacity

// stop conditions, proven exactly equivalent to the reference comparisons:
//   frac<0.12 stops at cnt>=31458 ; frac>0.08 stops at cnt<=20971
#define STOP_HI 31458
#define STOP_LO 20971
// rank constants: FRAG_PIX - STOP_*
#define RANK_HI 230686u   // 262144-31458
#define RANK_LO 241173u   // 262144-20971

__device__ __forceinline__ int frag_of(int py, int px) {
  return ((py >> 9) << 3) + (px >> 9);
}

__device__ __forceinline__ int bin_of(float v) {
  int b = (int)(v * 8192.0f);   // monotone f32 map
  if (b < 0) b = 0;
  if (b > NBINS - 1) b = NBINS - 1;
  return b;
}

// ---------------------------------------------------------------------------
// 1) 5x5 box blur — VERIFIED bit-exact vs reference (numpy pairwise_sum n=25
//    tree over materialized (windows*k), row-major taps, OOB -> exact 0).
// ---------------------------------------------------------------------------
__global__ void blur_kernel(const float* __restrict__ x, float* __restrict__ out) {
  int idx = blockIdx.x * blockDim.x + threadIdx.x;
  int px = idx & (WW - 1);
  int py = idx >> 12;
  const float K = (float)(1.0 / 25.0);
  float p[25];
#pragma unroll
  for (int i = 0; i < 25; ++i) {
    int dy = i / 5 - 2;
    int dx = i % 5 - 2;
    int yy = py + dy;
    int xx = px + dx;
    float v = 0.0f;
    if ((unsigned)yy < (unsigned)HH && (unsigned)xx < (unsigned)WW) {
      v = x[yy * WW + xx];
    }
    p[i] = __fmul_rn(v, K);
  }
  float r0 = __fadd_rn(__fadd_rn(p[0], p[8]),  p[16]);
  float r1 = __fadd_rn(__fadd_rn(p[1], p[9]),  p[17]);
  float r2 = __fadd_rn(__fadd_rn(p[2], p[10]), p[18]);
  float r3 = __fadd_rn(__fadd_rn(p[3], p[11]), p[19]);
  float r4 = __fadd_rn(__fadd_rn(p[4], p[12]), p[20]);
  float r5 = __fadd_rn(__fadd_rn(p[5], p[13]), p[21]);
  float r6 = __fadd_rn(__fadd_rn(p[6], p[14]), p[22]);
  float r7 = __fadd_rn(__fadd_rn(p[7], p[15]), p[23]);
  float res = __fadd_rn(
      __fadd_rn(__fadd_rn(r0, r1), __fadd_rn(r2, r3)),
      __fadd_rn(__fadd_rn(r4, r5), __fadd_rn(r6, r7)));
  res = __fadd_rn(res, p[24]);
  out[idx] = res;
}

// ---------------------------------------------------------------------------
// 2a) per-fragment histogram (8192 bins)
// ---------------------------------------------------------------------------
__global__ void hist_kernel(const float* __restrict__ blur, uint32_t* __restrict__ hist) {
  int idx = blockIdx.x * blockDim.x + threadIdx.x;
  float v = blur[idx];
  int f = frag_of(idx >> 12, idx & (WW - 1));
  atomicAdd(&hist[f * NBINS + bin_of(v)], 1u);
}

// ---------------------------------------------------------------------------
// 2b) per-fragment exclusive prefix -> P[f][0..8192]
// ---------------------------------------------------------------------------
__global__ void prefix_kernel(const uint32_t* __restrict__ hist, uint32_t* __restrict__ P) {
  int f = blockIdx.x;
  int tid = threadIdx.x;  // 256 threads, 32 bins each
  const uint32_t* hf = hist + f * NBINS;
  uint32_t* Pf = P + f * (NBINS + 1);
  __shared__ uint32_t segsum[256];
  __shared__ uint32_t segoff[256];
  int base = tid * 32;
  uint32_t s = 0;
  for (int i = 0; i < 32; ++i) s += hf[base + i];
  segsum[tid] = s;
  __syncthreads();
  if (tid == 0) {
    uint32_t a = 0;
    for (int i = 0; i < 256; ++i) { segoff[i] = a; a += segsum[i]; }
  }
  __syncthreads();
  uint32_t off = segoff[tid];
  for (int i = 0; i < 32; ++i) {
    Pf[base + i] = off;
    off += hf[base + i];
  }
  if (tid == 255) Pf[NBINS] = off;   // == FRAG_PIX
}

// ---------------------------------------------------------------------------
// 2c) gather critical-bucket values. A rung decision is ambiguous (needs
//     exact in-bucket counting) ONLY in the unique bucket straddling each
//     rank constant:
//       phase 0:  P[b] <= 230686 < P[b+1]
//       phase 1:  P[b] <  241173 <= P[b+1]
//     Collect those buckets' values per fragment (expected ~100-200, cap 4096).
// ---------------------------------------------------------------------------
__global__ void gather_kernel(const float* __restrict__ blur,
                              const uint32_t* __restrict__ P,
                              float* __restrict__ band,
                              uint32_t* __restrict__ bandcnt) {
  int idx = blockIdx.x * blockDim.x + threadIdx.x;
  float v = blur[idx];
  int f = frag_of(idx >> 12, idx & (WW - 1));
  int b = bin_of(v);
  const uint32_t* Pf = P + f * (NBINS + 1);
  uint32_t Pb = Pf[b];
  uint32_t Pb1 = Pf[b + 1];
  bool critA = (Pb <= RANK_HI) && (Pb1 > RANK_HI);
  bool critB = (Pb < RANK_LO) && (Pb1 >= RANK_LO);
  if (critA || critB) {
    uint32_t pos = atomicAdd(&bandcnt[f], 1u);
    if (pos < CAP) band[(size_t)f * CAP + pos] = v;
  }
}

// ---------------------------------------------------------------------------
// 3) threshold walk — ONE WAVE. Per 64-rung batch: exact f32 ladder, per-lane
//    histogram lookup P[b],P[b+1]; cnt = A = FRAG_PIX-P[b+1] decides exactly
//    unless [A, A+hist[b]] straddles the stop constant, in which case the
//    critical-band LDS values give the exact in-bucket count. Decisions are
//    bit-identical to the reference while-loops.
// ---------------------------------------------------------------------------
__global__ void walk_kernel(const uint32_t* __restrict__ P,
                            const float* __restrict__ band,
                            const uint32_t* __restrict__ bandcnt,
                            float* __restrict__ th_out) {
  __shared__ float lds_band[CAP];
  int lane = threadIdx.x;   // 64 threads, one wave
  float th = 0.5f;          // TH1_INIT
  for (int f = 0; f < NFRAG; ++f) {
    const uint32_t* Pf = P + f * (NBINS + 1);
    int cnt_f = (int)bandcnt[f];
    if (cnt_f > CAP) cnt_f = CAP;
    __syncthreads();
    for (int i = lane; i < cnt_f; i += 64) lds_band[i] = band[(size_t)f * CAP + i];
    __syncthreads();
    for (int phase = 0; phase < 2; ++phase) {
      const float step = (phase == 0) ? -0.0005f : 0.0005f;
      for (;;) {
        float r = th;
        for (int i = 0; i < lane; ++i) r = __fadd_rn(r, step);  // exact ladder
        int b = bin_of(r);
        uint32_t Pb = Pf[b];
        uint32_t Pb1 = Pf[b + 1];
        int A = FRAG_PIX - (int)Pb1;
        int Hc = (int)(Pb1 - Pb);
        bool amb = (phase == 0) ? (A < STOP_HI && A + Hc >= STOP_HI)
                                : (A <= STOP_LO && A + Hc > STOP_LO);
        int cnt = A;
        if (amb) {
          int c = 0;
          for (int i = 0; i < cnt_f; ++i) {
            float w = lds_band[i];
            if (bin_of(w) == b && w > r) ++c;
          }
          cnt = A + c;
        }
        bool stop = (phase == 0) ? (cnt >= STOP_HI) : (cnt <= STOP_LO);
        unsigned long long bal = __ballot(stop);
        if (bal) { th = __shfl(r, __ffsll(bal) - 1); break; }
        th = __fadd_rn(__shfl(r, 63), step);
      }
    }
    if (lane == 0) th_out[f] = th;
  }
}

// ---------------------------------------------------------------------------
// 4) mask + bit-pack via wave ballot (64 consecutive px per u64 word)
// ---------------------------------------------------------------------------
__global__ void mask_pack_kernel(const float* __restrict__ blur,
                                 const float* __restrict__ th,
                                 unsigned long long* __restrict__ pk) {
  int idx = blockIdx.x * blockDim.x + threadIdx.x;
  int px = idx & (WW - 1);
  int py = idx >> 12;
  bool on = blur[idx] > th[frag_of(py, px)];
  unsigned long long w = __ballot(on);
  if ((threadIdx.x & 63) == 0) pk[idx >> 6] = w;
}

// ---------------------------------------------------------------------------
// 5) packed 5x5 morphology. Dilate = vmax(hmax(.)) with OOB=0.
//    Erode = ~dilate(~x) (De Morgan handles the clipped window exactly).
// ---------------------------------------------------------------------------
template <bool COMP>
__global__ void hmax_kernel(const unsigned long long* __restrict__ in,
                            unsigned long long* __restrict__ out) {
  int w = blockIdx.x * blockDim.x + threadIdx.x;
  if (w >= NWORDS) return;
  int wx = w & (WPR - 1);
  unsigned long long m = COMP ? ~in[w] : in[w];
  unsigned long long l = (wx > 0) ? (COMP ? ~in[w - 1] : in[w - 1]) : 0ull;
  unsigned long long r = (wx < WPR - 1) ? (COMP ? ~in[w + 1] : in[w + 1]) : 0ull;
  out[w] = m | (m << 1) | (m << 2) | (m >> 1) | (m >> 2)
             | (l >> 62) | (l >> 63) | (r << 62) | (r << 63);
}

__global__ void vmax_kernel(const unsigned long long* __restrict__ in,
                            unsigned long long* __restrict__ out) {
  int w = blockIdx.x * blockDim.x + threadIdx.x;
  if (w >= NWORDS) return;
  int wy = w >> 6;
  int wx = w & (WPR - 1);
  unsigned long long res = 0ull;
#pragma unroll
  for (int d = -2; d <= 2; ++d) {
    int yy = wy + d;
    if ((unsigned)yy < (unsigned)HH) res |= in[yy * WPR + wx];
  }
  out[w] = res;
}

// final unpack; folds the trailing complement of the erode De Morgan pair
__global__ void unpack_kernel(const unsigned long long* __restrict__ in,
                              float* __restrict__ out) {
  int idx = blockIdx.x * blockDim.x + threadIdx.x;
  unsigned long long w = in[idx >> 6];
  int bit = (int)((w >> (idx & 63)) & 1ull);
  out[idx] = (float)(1 - bit);
}

// ---------------------------------------------------------------------------
extern "C" void kernel_launch(void* const* d_in, const int* in_sizes, int n_in,
                              void* d_out, int out_size, void* d_ws, size_t ws_size,
                              hipStream_t stream) {
  const float* x = (const float*)d_in[0];
  if (n_in > 1 && in_sizes[0] != NPIX) x = (const float*)d_in[1];
  float* out = (float*)d_out;
  char* ws = (char*)d_ws;

  // workspace layout — TOTAL ~9.4 MB
  const size_t OFF_HIST = 0;          // 64*8192*4   = 2,097,152
  const size_t OFF_P    = 2097152;    // 64*8193*4   = 2,097,408
  const size_t OFF_TH   = 4194560;    // 256
  const size_t OFF_PKA  = 4194816;    // 2,097,152
  const size_t OFF_PKB  = 6291968;    // 2,097,152
  const size_t OFF_BCNT = 8389120;    // 256
  const size_t OFF_BAND = 8389376;    // 64*4096*4 = 1,048,576 (end 9,437,952)
  uint32_t* hist    = (uint32_t*)(ws + OFF_HIST);
  uint32_t* P       = (uint32_t*)(ws + OFF_P);
  float*    th      = (float*)(ws + OFF_TH);
  unsigned long long* PKA = (unsigned long long*)(ws + OFF_PKA);
  unsigned long long* PKB = (unsigned long long*)(ws + OFF_PKB);
  uint32_t* bandcnt = (uint32_t*)(ws + OFF_BCNT);
  float*    band    = (float*)(ws + OFF_BAND);

  float* blurred = out;   // blur lives in d_out; unpack rewrites it at the end

  const int TPB = 256;
  const int NB = NPIX / TPB;       // 65536
  const int NBW = NWORDS / TPB;    // 1024

  blur_kernel<<<NB, TPB, 0, stream>>>(x, blurred);
  hipMemsetAsync(hist, 0, (size_t)NFRAG * NBINS * sizeof(uint32_t), stream);
  hipMemsetAsync(bandcnt, 0, NFRAG * sizeof(uint32_t), stream);
  hist_kernel<<<NB, TPB, 0, stream>>>(blurred, hist);
  prefix_kernel<<<NFRAG, 256, 0, stream>>>(hist, P);
  gather_kernel<<<NB, TPB, 0, stream>>>(blurred, P, band, bandcnt);
  walk_kernel<<<1, 64, 0, stream>>>(P, band, bandcnt, th);
  mask_pack_kernel<<<NB, TPB, 0, stream>>>(blurred, th, PKA);
  hmax_kernel<false><<<NBW, TPB, 0, stream>>>(PKA, PKB);  // dilate H
  vmax_kernel<<<NBW, TPB, 0, stream>>>(PKB, PKA);         // dilate V
  hmax_kernel<true><<<NBW, TPB, 0, stream>>>(PKA, PKB);   // erode H (complement in)
  vmax_kernel<<<NBW, TPB, 0, stream>>>(PKB, PKA);         // erode V
  unpack_kernel<<<NB, TPB, 0, stream>>>(PKA, out);        // out = ~bit
}

// Round 10
// 1083.319 us; speedup vs baseline: 51.8246x; 2.0691x over previous
//
#include <hip/hip_runtime.h>
#include <stdint.h>

#define HH 4096
#define WW 4096
#define NPIX (HH * WW)
#define NBINS 8192
#define NFRAG 64
#define FRAG_PIX (512 * 512)   // 2^18
#define WPR 64                 // u64 words per row (4096/64)
#define NWORDS (HH * WPR)      // 262144
#define CAP 4096               // per-fragment critical-band capacity

// stop conditions, proven exactly equivalent to the reference comparisons:
//   frac<0.12 stops at cnt>=31458 ; frac>0.08 stops at cnt<=20971
#define STOP_HI 31458
#define STOP_LO 20971
// rank constants: FRAG_PIX - STOP_*
#define RANK_HI 230686u   // 262144-31458
#define RANK_LO 241173u   // 262144-20971

__device__ __forceinline__ int frag_of(int py, int px) {
  return ((py >> 9) << 3) + (px >> 9);
}

__device__ __forceinline__ int bin_of(float v) {
  int b = (int)(v * 8192.0f);   // monotone f32 map
  if (b < 0) b = 0;
  if (b > NBINS - 1) b = NBINS - 1;
  return b;
}

// ---------------------------------------------------------------------------
// 1) 5x5 box blur — VERIFIED bit-exact vs reference (numpy pairwise_sum n=25
//    tree over materialized (windows*k), row-major taps, OOB -> exact 0).
//    DO NOT TOUCH THE ARITHMETIC.
// ---------------------------------------------------------------------------
__global__ void blur_kernel(const float* __restrict__ x, float* __restrict__ out) {
  int idx = blockIdx.x * blockDim.x + threadIdx.x;
  int px = idx & (WW - 1);
  int py = idx >> 12;
  const float K = (float)(1.0 / 25.0);
  float p[25];
#pragma unroll
  for (int i = 0; i < 25; ++i) {
    int dy = i / 5 - 2;
    int dx = i % 5 - 2;
    int yy = py + dy;
    int xx = px + dx;
    float v = 0.0f;
    if ((unsigned)yy < (unsigned)HH && (unsigned)xx < (unsigned)WW) {
      v = x[yy * WW + xx];
    }
    p[i] = __fmul_rn(v, K);
  }
  float r0 = __fadd_rn(__fadd_rn(p[0], p[8]),  p[16]);
  float r1 = __fadd_rn(__fadd_rn(p[1], p[9]),  p[17]);
  float r2 = __fadd_rn(__fadd_rn(p[2], p[10]), p[18]);
  float r3 = __fadd_rn(__fadd_rn(p[3], p[11]), p[19]);
  float r4 = __fadd_rn(__fadd_rn(p[4], p[12]), p[20]);
  float r5 = __fadd_rn(__fadd_rn(p[5], p[13]), p[21]);
  float r6 = __fadd_rn(__fadd_rn(p[6], p[14]), p[22]);
  float r7 = __fadd_rn(__fadd_rn(p[7], p[15]), p[23]);
  float res = __fadd_rn(
      __fadd_rn(__fadd_rn(r0, r1), __fadd_rn(r2, r3)),
      __fadd_rn(__fadd_rn(r4, r5), __fadd_rn(r6, r7)));
  res = __fadd_rn(res, p[24]);
  out[idx] = res;
}

// ---------------------------------------------------------------------------
// 2a) per-fragment histogram — LDS-privatized.
//     256 blocks; block b owns quarter q=b&3 of fragment f=b>>2
//     (rows fi*512+q*128 .. +128, cols fj*512 .. +512). Private 8192-bin LDS
//     hist, then merge non-zero bins into global with one atomicAdd each.
// ---------------------------------------------------------------------------
__global__ void hist_kernel(const float* __restrict__ blur, uint32_t* __restrict__ hist) {
  __shared__ uint32_t lh[NBINS];
  int tid = threadIdx.x;
  for (int i = tid; i < NBINS; i += 256) lh[i] = 0;
  __syncthreads();
  int f = blockIdx.x >> 2;
  int q = blockIdx.x & 3;
  int row0 = (f >> 3) * 512 + q * 128;
  int col0 = (f & 7) * 512;
  const float* base = blur + (size_t)row0 * WW + col0;
  // 128 rows x 512 cols = 16384 float4s, 64 per thread
  for (int it = tid; it < 128 * 128; it += 256) {
    int rr = it >> 7;           // row 0..127
    int c4 = it & 127;          // float4 col 0..127
    float4 v4 = *(const float4*)(base + (size_t)rr * WW + c4 * 4);
    atomicAdd(&lh[bin_of(v4.x)], 1u);
    atomicAdd(&lh[bin_of(v4.y)], 1u);
    atomicAdd(&lh[bin_of(v4.z)], 1u);
    atomicAdd(&lh[bin_of(v4.w)], 1u);
  }
  __syncthreads();
  uint32_t* hf = hist + f * NBINS;
  for (int i = tid; i < NBINS; i += 256) {
    uint32_t c = lh[i];
    if (c) atomicAdd(&hf[i], c);
  }
}

// ---------------------------------------------------------------------------
// 2b) per-fragment exclusive prefix -> P[f][0..8192]
// ---------------------------------------------------------------------------
__global__ void prefix_kernel(const uint32_t* __restrict__ hist, uint32_t* __restrict__ P) {
  int f = blockIdx.x;
  int tid = threadIdx.x;  // 256 threads, 32 bins each
  const uint32_t* hf = hist + f * NBINS;
  uint32_t* Pf = P + f * (NBINS + 1);
  __shared__ uint32_t segsum[256];
  __shared__ uint32_t segoff[256];
  int base = tid * 32;
  uint32_t s = 0;
  for (int i = 0; i < 32; ++i) s += hf[base + i];
  segsum[tid] = s;
  __syncthreads();
  if (tid == 0) {
    uint32_t a = 0;
    for (int i = 0; i < 256; ++i) { segoff[i] = a; a += segsum[i]; }
  }
  __syncthreads();
  uint32_t off = segoff[tid];
  for (int i = 0; i < 32; ++i) {
    Pf[base + i] = off;
    off += hf[base + i];
  }
  if (tid == 255) Pf[NBINS] = off;   // == FRAG_PIX
}

// ---------------------------------------------------------------------------
// 2c) gather critical-bucket values (buckets straddling the rank constants).
// ---------------------------------------------------------------------------
__global__ void gather_kernel(const float* __restrict__ blur,
                              const uint32_t* __restrict__ P,
                              float* __restrict__ band,
                              uint32_t* __restrict__ bandcnt) {
  int idx = blockIdx.x * blockDim.x + threadIdx.x;
  float v = blur[idx];
  int f = frag_of(idx >> 12, idx & (WW - 1));
  int b = bin_of(v);
  const uint32_t* Pf = P + f * (NBINS + 1);
  uint32_t Pb = Pf[b];
  uint32_t Pb1 = Pf[b + 1];
  bool critA = (Pb <= RANK_HI) && (Pb1 > RANK_HI);
  bool critB = (Pb < RANK_LO) && (Pb1 >= RANK_LO);
  if (critA || critB) {
    uint32_t pos = atomicAdd(&bandcnt[f], 1u);
    if (pos < CAP) band[(size_t)f * CAP + pos] = v;
  }
}

// ---------------------------------------------------------------------------
// 3) threshold walk — ONE WAVE, histogram-driven, exact (see R9).
// ---------------------------------------------------------------------------
__global__ void walk_kernel(const uint32_t* __restrict__ P,
                            const float* __restrict__ band,
                            const uint32_t* __restrict__ bandcnt,
                            float* __restrict__ th_out) {
  __shared__ float lds_band[CAP];
  int lane = threadIdx.x;   // 64 threads, one wave
  float th = 0.5f;          // TH1_INIT
  for (int f = 0; f < NFRAG; ++f) {
    const uint32_t* Pf = P + f * (NBINS + 1);
    int cnt_f = (int)bandcnt[f];
    if (cnt_f > CAP) cnt_f = CAP;
    __syncthreads();
    for (int i = lane; i < cnt_f; i += 64) lds_band[i] = band[(size_t)f * CAP + i];
    __syncthreads();
    for (int phase = 0; phase < 2; ++phase) {
      const float step = (phase == 0) ? -0.0005f : 0.0005f;
      for (;;) {
        float r = th;
        for (int i = 0; i < lane; ++i) r = __fadd_rn(r, step);  // exact ladder
        int b = bin_of(r);
        uint32_t Pb = Pf[b];
        uint32_t Pb1 = Pf[b + 1];
        int A = FRAG_PIX - (int)Pb1;
        int Hc = (int)(Pb1 - Pb);
        bool amb = (phase == 0) ? (A < STOP_HI && A + Hc >= STOP_HI)
                                : (A <= STOP_LO && A + Hc > STOP_LO);
        int cnt = A;
        if (amb) {
          int c = 0;
          for (int i = 0; i < cnt_f; ++i) {
            float w = lds_band[i];
            if (bin_of(w) == b && w > r) ++c;
          }
          cnt = A + c;
        }
        bool stop = (phase == 0) ? (cnt >= STOP_HI) : (cnt <= STOP_LO);
        unsigned long long bal = __ballot(stop);
        if (bal) { th = __shfl(r, __ffsll(bal) - 1); break; }
        th = __fadd_rn(__shfl(r, 63), step);
      }
    }
    if (lane == 0) th_out[f] = th;
  }
}

// ---------------------------------------------------------------------------
// 4) mask + bit-pack via wave ballot (64 consecutive px per u64 word)
// ---------------------------------------------------------------------------
__global__ void mask_pack_kernel(const float* __restrict__ blur,
                                 const float* __restrict__ th,
                                 unsigned long long* __restrict__ pk) {
  int idx = blockIdx.x * blockDim.x + threadIdx.x;
  int px = idx & (WW - 1);
  int py = idx >> 12;
  bool on = blur[idx] > th[frag_of(py, px)];
  unsigned long long w = __ballot(on);
  if ((threadIdx.x & 63) == 0) pk[idx >> 6] = w;
}

// ---------------------------------------------------------------------------
// 5) packed 5x5 morphology. Dilate = vmax(hmax(.)) with OOB=0.
//    Erode = ~dilate(~x) (De Morgan handles the clipped window exactly).
// ---------------------------------------------------------------------------
template <bool COMP>
__global__ void hmax_kernel(const unsigned long long* __restrict__ in,
                            unsigned long long* __restrict__ out) {
  int w = blockIdx.x * blockDim.x + threadIdx.x;
  if (w >= NWORDS) return;
  int wx = w & (WPR - 1);
  unsigned long long m = COMP ? ~in[w] : in[w];
  unsigned long long l = (wx > 0) ? (COMP ? ~in[w - 1] : in[w - 1]) : 0ull;
  unsigned long long r = (wx < WPR - 1) ? (COMP ? ~in[w + 1] : in[w + 1]) : 0ull;
  out[w] = m | (m << 1) | (m << 2) | (m >> 1) | (m >> 2)
             | (l >> 62) | (l >> 63) | (r << 62) | (r << 63);
}

__global__ void vmax_kernel(const unsigned long long* __restrict__ in,
                            unsigned long long* __restrict__ out) {
  int w = blockIdx.x * blockDim.x + threadIdx.x;
  if (w >= NWORDS) return;
  int wy = w >> 6;
  int wx = w & (WPR - 1);
  unsigned long long res = 0ull;
#pragma unroll
  for (int d = -2; d <= 2; ++d) {
    int yy = wy + d;
    if ((unsigned)yy < (unsigned)HH) res |= in[yy * WPR + wx];
  }
  out[w] = res;
}

// final unpack; folds the trailing complement of the erode De Morgan pair
__global__ void unpack_kernel(const unsigned long long* __restrict__ in,
                              float* __restrict__ out) {
  int idx = blockIdx.x * blockDim.x + threadIdx.x;
  unsigned long long w = in[idx >> 6];
  int bit = (int)((w >> (idx & 63)) & 1ull);
  out[idx] = (float)(1 - bit);
}

// ---------------------------------------------------------------------------
extern "C" void kernel_launch(void* const* d_in, const int* in_sizes, int n_in,
                              void* d_out, int out_size, void* d_ws, size_t ws_size,
                              hipStream_t stream) {
  const float* x = (const float*)d_in[0];
  if (n_in > 1 && in_sizes[0] != NPIX) x = (const float*)d_in[1];
  float* out = (float*)d_out;
  char* ws = (char*)d_ws;

  // workspace layout — TOTAL ~9.4 MB
  const size_t OFF_HIST = 0;          // 64*8192*4   = 2,097,152
  const size_t OFF_P    = 2097152;    // 64*8193*4   = 2,097,408
  const size_t OFF_TH   = 4194560;    // 256
  const size_t OFF_PKA  = 4194816;    // 2,097,152
  const size_t OFF_PKB  = 6291968;    // 2,097,152
  const size_t OFF_BCNT = 8389120;    // 256
  const size_t OFF_BAND = 8389376;    // 64*4096*4 = 1,048,576 (end 9,437,952)
  uint32_t* hist    = (uint32_t*)(ws + OFF_HIST);
  uint32_t* P       = (uint32_t*)(ws + OFF_P);
  float*    th      = (float*)(ws + OFF_TH);
  unsigned long long* PKA = (unsigned long long*)(ws + OFF_PKA);
  unsigned long long* PKB = (unsigned long long*)(ws + OFF_PKB);
  uint32_t* bandcnt = (uint32_t*)(ws + OFF_BCNT);
  float*    band    = (float*)(ws + OFF_BAND);

  float* blurred = out;   // blur lives in d_out; unpack rewrites it at the end

  const int TPB = 256;
  const int NB = NPIX / TPB;       // 65536
  const int NBW = NWORDS / TPB;    // 1024

  blur_kernel<<<NB, TPB, 0, stream>>>(x, blurred);
  hipMemsetAsync(hist, 0, (size_t)NFRAG * NBINS * sizeof(uint32_t), stream);
  hipMemsetAsync(bandcnt, 0, NFRAG * sizeof(uint32_t), stream);
  hist_kernel<<<256, TPB, 0, stream>>>(blurred, hist);
  prefix_kernel<<<NFRAG, 256, 0, stream>>>(hist, P);
  gather_kernel<<<NB, TPB, 0, stream>>>(blurred, P, band, bandcnt);
  walk_kernel<<<1, 64, 0, stream>>>(P, band, bandcnt, th);
  mask_pack_kernel<<<NB, TPB, 0, stream>>>(blurred, th, PKA);
  hmax_kernel<false><<<NBW, TPB, 0, stream>>>(PKA, PKB);  // dilate H
  vmax_kernel<<<NBW, TPB, 0, stream>>>(PKB, PKA);         // dilate V
  hmax_kernel<true><<<NBW, TPB, 0, stream>>>(PKA, PKB);   // erode H (complement in)
  vmax_kernel<<<NBW, TPB, 0, stream>>>(PKB, PKA);         // erode V
  unpack_kernel<<<NB, TPB, 0, stream>>>(PKA, out);        // out = ~bit
}

// Round 11
// 748.007 us; speedup vs baseline: 75.0562x; 1.4483x over previous
//
#include <hip/hip_runtime.h>
#include <stdint.h>

#define HH 4096
#define WW 4096
#define NPIX (HH * WW)
#define NBINS 8192
#define NFRAG 64
#define FRAG_PIX (512 * 512)   // 2^18
#define WPR 64                 // u64 words per row (4096/64)
#define NWORDS (HH * WPR)      // 262144
#define CAP 4096               // per-fragment critical-band capacity

// Reference stop conditions (integer-exact):
//   phase0 stop: cnt >= 31458 ; phase1 stop: cnt <= 20971
// Order-statistic form (proven equivalent, strict compares):
//   phase0 stop(r) <=> r < V_HI,  V_HI = v_sorted[230686]
//   phase1 stop(r) <=> r >= V_LO, V_LO = v_sorted[241172]
#define RANK_HI 230686   // 262144-31458
#define RANK_LO 241172   // 262144-20972

__device__ __forceinline__ int frag_of(int py, int px) {
  return ((py >> 9) << 3) + (px >> 9);
}

__device__ __forceinline__ int bin_of(float v) {
  int b = (int)(v * 8192.0f);   // monotone f32 map
  if (b < 0) b = 0;
  if (b > NBINS - 1) b = NBINS - 1;
  return b;
}

// ---------------------------------------------------------------------------
// 1) 5x5 box blur — VERIFIED bit-exact (numpy pairwise_sum n=25 tree over
//    materialized (windows*k), row-major taps, OOB -> exact 0). DO NOT TOUCH.
// ---------------------------------------------------------------------------
__global__ void blur_kernel(const float* __restrict__ x, float* __restrict__ out) {
  int idx = blockIdx.x * blockDim.x + threadIdx.x;
  int px = idx & (WW - 1);
  int py = idx >> 12;
  const float K = (float)(1.0 / 25.0);
  float p[25];
#pragma unroll
  for (int i = 0; i < 25; ++i) {
    int dy = i / 5 - 2;
    int dx = i % 5 - 2;
    int yy = py + dy;
    int xx = px + dx;
    float v = 0.0f;
    if ((unsigned)yy < (unsigned)HH && (unsigned)xx < (unsigned)WW) {
      v = x[yy * WW + xx];
    }
    p[i] = __fmul_rn(v, K);
  }
  float r0 = __fadd_rn(__fadd_rn(p[0], p[8]),  p[16]);
  float r1 = __fadd_rn(__fadd_rn(p[1], p[9]),  p[17]);
  float r2 = __fadd_rn(__fadd_rn(p[2], p[10]), p[18]);
  float r3 = __fadd_rn(__fadd_rn(p[3], p[11]), p[19]);
  float r4 = __fadd_rn(__fadd_rn(p[4], p[12]), p[20]);
  float r5 = __fadd_rn(__fadd_rn(p[5], p[13]), p[21]);
  float r6 = __fadd_rn(__fadd_rn(p[6], p[14]), p[22]);
  float r7 = __fadd_rn(__fadd_rn(p[7], p[15]), p[23]);
  float res = __fadd_rn(
      __fadd_rn(__fadd_rn(r0, r1), __fadd_rn(r2, r3)),
      __fadd_rn(__fadd_rn(r4, r5), __fadd_rn(r6, r7)));
  res = __fadd_rn(res, p[24]);
  out[idx] = res;
}

// ---------------------------------------------------------------------------
// 2a) per-fragment histogram — LDS-privatized (256 blocks, quarter-fragment
//     per block, merge non-zero bins with one global atomic each).
// ---------------------------------------------------------------------------
__global__ void hist_kernel(const float* __restrict__ blur, uint32_t* __restrict__ hist) {
  __shared__ uint32_t lh[NBINS];
  int tid = threadIdx.x;
  for (int i = tid; i < NBINS; i += 256) lh[i] = 0;
  __syncthreads();
  int f = blockIdx.x >> 2;
  int q = blockIdx.x & 3;
  int row0 = (f >> 3) * 512 + q * 128;
  int col0 = (f & 7) * 512;
  const float* base = blur + (size_t)row0 * WW + col0;
  for (int it = tid; it < 128 * 128; it += 256) {
    int rr = it >> 7;
    int c4 = it & 127;
    float4 v4 = *(const float4*)(base + (size_t)rr * WW + c4 * 4);
    atomicAdd(&lh[bin_of(v4.x)], 1u);
    atomicAdd(&lh[bin_of(v4.y)], 1u);
    atomicAdd(&lh[bin_of(v4.z)], 1u);
    atomicAdd(&lh[bin_of(v4.w)], 1u);
  }
  __syncthreads();
  uint32_t* hf = hist + f * NBINS;
  for (int i = tid; i < NBINS; i += 256) {
    uint32_t c = lh[i];
    if (c) atomicAdd(&hf[i], c);
  }
}

// ---------------------------------------------------------------------------
// 2b) per-fragment exclusive prefix -> P[f][0..8192]
// ---------------------------------------------------------------------------
__global__ void prefix_kernel(const uint32_t* __restrict__ hist, uint32_t* __restrict__ P) {
  int f = blockIdx.x;
  int tid = threadIdx.x;
  const uint32_t* hf = hist + f * NBINS;
  uint32_t* Pf = P + f * (NBINS + 1);
  __shared__ uint32_t segsum[256];
  __shared__ uint32_t segoff[256];
  int base = tid * 32;
  uint32_t s = 0;
  for (int i = 0; i < 32; ++i) s += hf[base + i];
  segsum[tid] = s;
  __syncthreads();
  if (tid == 0) {
    uint32_t a = 0;
    for (int i = 0; i < 256; ++i) { segoff[i] = a; a += segsum[i]; }
  }
  __syncthreads();
  uint32_t off = segoff[tid];
  for (int i = 0; i < 32; ++i) {
    Pf[base + i] = off;
    off += hf[base + i];
  }
  if (tid == 255) Pf[NBINS] = off;   // == FRAG_PIX
}

// ---------------------------------------------------------------------------
// 2c) find the critical buckets + local ranks per fragment (binary search).
//     bins4[f] = (bhi, blo, khi, klo):  P[bhi] <= RANK_HI < P[bhi+1],
//     khi = RANK_HI - P[bhi]  (same for LO).
// ---------------------------------------------------------------------------
__global__ void findbins_kernel(const uint32_t* __restrict__ P, int4* __restrict__ bins4) {
  int f = threadIdx.x;   // 64 threads
  if (f >= NFRAG) return;
  const uint32_t* Pf = P + f * (NBINS + 1);
  int lo, hi, bhi, blo;
  // largest b with P[b] <= RANK_HI  (P[b+1] > RANK_HI)
  lo = 0; hi = NBINS - 1;
  while (lo < hi) {
    int mid = (lo + hi + 1) >> 1;
    if (Pf[mid] <= RANK_HI) lo = mid; else hi = mid - 1;
  }
  bhi = lo;
  lo = 0; hi = NBINS - 1;
  while (lo < hi) {
    int mid = (lo + hi + 1) >> 1;
    if (Pf[mid] <= RANK_LO) lo = mid; else hi = mid - 1;
  }
  blo = lo;
  int4 r;
  r.x = bhi;
  r.y = blo;
  r.z = RANK_HI - (int)Pf[bhi];
  r.w = RANK_LO - (int)Pf[blo];
  bins4[f] = r;
}

// ---------------------------------------------------------------------------
// 2d) gather critical-bucket values (bin-ID compare vs 1KB cached table)
// ---------------------------------------------------------------------------
__global__ void gather_kernel(const float* __restrict__ blur,
                              const int4* __restrict__ bins4,
                              float* __restrict__ band,
                              uint32_t* __restrict__ bandcnt) {
  int idx = blockIdx.x * blockDim.x + threadIdx.x;
  float v = blur[idx];
  int f = frag_of(idx >> 12, idx & (WW - 1));
  int4 info = bins4[f];
  int b = bin_of(v);
  if (b == info.x || b == info.y) {
    uint32_t pos = atomicAdd(&bandcnt[f], 1u);
    if (pos < CAP) band[(size_t)f * CAP + pos] = v;
  }
}

// ---------------------------------------------------------------------------
// 2e) exact order-statistic selection within the critical buckets.
//     count-based selection: V s.t. #{w<V} <= k < #{w<=V} among bucket values.
// ---------------------------------------------------------------------------
__global__ void select_kernel(const float* __restrict__ band,
                              const uint32_t* __restrict__ bandcnt,
                              const int4* __restrict__ bins4,
                              float2* __restrict__ vhl) {
  __shared__ float wv[CAP];
  __shared__ float res[2];
  int f = blockIdx.x;
  int tid = threadIdx.x;
  int n = (int)bandcnt[f];
  if (n > CAP) n = CAP;
  for (int i = tid; i < n; i += 256) wv[i] = band[(size_t)f * CAP + i];
  __syncthreads();
  int4 info = bins4[f];
#pragma unroll
  for (int sel = 0; sel < 2; ++sel) {
    int tb = sel ? info.y : info.x;
    int k  = sel ? info.w : info.z;
    for (int i = tid; i < n; i += 256) {
      float w = wv[i];
      if (bin_of(w) != tb) continue;
      int less = 0, leq = 0;
      for (int j = 0; j < n; ++j) {
        float u = wv[j];
        if (bin_of(u) == tb) {
          less += (u < w) ? 1 : 0;
          leq  += (u <= w) ? 1 : 0;
        }
      }
      if (less <= k && k < leq) res[sel] = w;   // unique value; benign race
    }
  }
  __syncthreads();
  if (tid == 0) vhl[f] = make_float2(res[0], res[1]);
}

// ---------------------------------------------------------------------------
// 3) threshold walk — ONE WAVE, pure ALU. stop0(r) <=> r < V_HI ;
//    stop1(r) <=> r >= V_LO. Ladder bit-identical to reference while-loops.
// ---------------------------------------------------------------------------
__global__ void walk_kernel(const float2* __restrict__ vhl, float* __restrict__ th_out) {
  int lane = threadIdx.x;   // 64 threads, one wave
  float2 mine = vhl[lane];  // lane f holds fragment f's (V_HI, V_LO)
  float th = 0.5f;          // TH1_INIT
  for (int f = 0; f < NFRAG; ++f) {
    float VH = __shfl(mine.x, f);
    float VL = __shfl(mine.y, f);
    // phase 0: while cnt<31458: th -= 0.0005  (stop: r < VH)
    for (;;) {
      float r = th;
      for (int i = 0; i < lane; ++i) r = __fadd_rn(r, -0.0005f);
      unsigned long long bal = __ballot(r < VH);
      if (bal) { th = __shfl(r, __ffsll(bal) - 1); break; }
      th = __fadd_rn(__shfl(r, 63), -0.0005f);
    }
    // phase 1: while cnt>20971: th += 0.0005  (stop: r >= VL)
    for (;;) {
      float r = th;
      for (int i = 0; i < lane; ++i) r = __fadd_rn(r, 0.0005f);
      unsigned long long bal = __ballot(r >= VL);
      if (bal) { th = __shfl(r, __ffsll(bal) - 1); break; }
      th = __fadd_rn(__shfl(r, 63), 0.0005f);
    }
    if (lane == 0) th_out[f] = th;
  }
}

// ---------------------------------------------------------------------------
// 4) mask + bit-pack via wave ballot (64 consecutive px per u64 word)
// ---------------------------------------------------------------------------
__global__ void mask_pack_kernel(const float* __restrict__ blur,
                                 const float* __restrict__ th,
                                 unsigned long long* __restrict__ pk) {
  int idx = blockIdx.x * blockDim.x + threadIdx.x;
  int px = idx & (WW - 1);
  int py = idx >> 12;
  bool on = blur[idx] > th[frag_of(py, px)];
  unsigned long long w = __ballot(on);
  if ((threadIdx.x & 63) == 0) pk[idx >> 6] = w;
}

// ---------------------------------------------------------------------------
// 5) packed 5x5 morphology. Dilate = vmax(hmax(.)) with OOB=0.
//    Erode = ~dilate(~x) (De Morgan handles the clipped window exactly).
// ---------------------------------------------------------------------------
template <bool COMP>
__global__ void hmax_kernel(const unsigned long long* __restrict__ in,
                            unsigned long long* __restrict__ out) {
  int w = blockIdx.x * blockDim.x + threadIdx.x;
  if (w >= NWORDS) return;
  int wx = w & (WPR - 1);
  unsigned long long m = COMP ? ~in[w] : in[w];
  unsigned long long l = (wx > 0) ? (COMP ? ~in[w - 1] : in[w - 1]) : 0ull;
  unsigned long long r = (wx < WPR - 1) ? (COMP ? ~in[w + 1] : in[w + 1]) : 0ull;
  out[w] = m | (m << 1) | (m << 2) | (m >> 1) | (m >> 2)
             | (l >> 62) | (l >> 63) | (r << 62) | (r << 63);
}

__global__ void vmax_kernel(const unsigned long long* __restrict__ in,
                            unsigned long long* __restrict__ out) {
  int w = blockIdx.x * blockDim.x + threadIdx.x;
  if (w >= NWORDS) return;
  int wy = w >> 6;
  int wx = w & (WPR - 1);
  unsigned long long res = 0ull;
#pragma unroll
  for (int d = -2; d <= 2; ++d) {
    int yy = wy + d;
    if ((unsigned)yy < (unsigned)HH) res |= in[yy * WPR + wx];
  }
  out[w] = res;
}

__global__ void unpack_kernel(const unsigned long long* __restrict__ in,
                              float* __restrict__ out) {
  int idx = blockIdx.x * blockDim.x + threadIdx.x;
  unsigned long long w = in[idx >> 6];
  int bit = (int)((w >> (idx & 63)) & 1ull);
  out[idx] = (float)(1 - bit);   // folds final complement of erode
}

// ---------------------------------------------------------------------------
extern "C" void kernel_launch(void* const* d_in, const int* in_sizes, int n_in,
                              void* d_out, int out_size, void* d_ws, size_t ws_size,
                              hipStream_t stream) {
  const float* x = (const float*)d_in[0];
  if (n_in > 1 && in_sizes[0] != NPIX) x = (const float*)d_in[1];
  float* out = (float*)d_out;
  char* ws = (char*)d_ws;

  // workspace layout — TOTAL ~9.4 MB
  const size_t OFF_HIST = 0;          // 2,097,152
  const size_t OFF_P    = 2097152;    // 2,097,408
  const size_t OFF_TH   = 4194560;    // 256
  const size_t OFF_PKA  = 4194816;    // 2,097,152
  const size_t OFF_PKB  = 6291968;    // 2,097,152
  const size_t OFF_BCNT = 8389120;    // 256
  const size_t OFF_BINS = 8389376;    // 64*16 = 1,024
  const size_t OFF_VHL  = 8390400;    // 64*8  = 512
  const size_t OFF_BAND = 8390912;    // 64*4096*4 = 1,048,576 (end ~9.44 MB)
  uint32_t* hist    = (uint32_t*)(ws + OFF_HIST);
  uint32_t* P       = (uint32_t*)(ws + OFF_P);
  float*    th      = (float*)(ws + OFF_TH);
  unsigned long long* PKA = (unsigned long long*)(ws + OFF_PKA);
  unsigned long long* PKB = (unsigned long long*)(ws + OFF_PKB);
  uint32_t* bandcnt = (uint32_t*)(ws + OFF_BCNT);
  int4*     bins4   = (int4*)(ws + OFF_BINS);
  float2*   vhl     = (float2*)(ws + OFF_VHL);
  float*    band    = (float*)(ws + OFF_BAND);

  float* blurred = out;   // blur lives in d_out; unpack rewrites it at the end

  const int TPB = 256;
  const int NB = NPIX / TPB;       // 65536
  const int NBW = NWORDS / TPB;    // 1024

  blur_kernel<<<NB, TPB, 0, stream>>>(x, blurred);
  hipMemsetAsync(hist, 0, (size_t)NFRAG * NBINS * sizeof(uint32_t), stream);
  hipMemsetAsync(bandcnt, 0, NFRAG * sizeof(uint32_t), stream);
  hist_kernel<<<256, TPB, 0, stream>>>(blurred, hist);
  prefix_kernel<<<NFRAG, 256, 0, stream>>>(hist, P);
  findbins_kernel<<<1, 64, 0, stream>>>(P, bins4);
  gather_kernel<<<NB, TPB, 0, stream>>>(blurred, bins4, band, bandcnt);
  select_kernel<<<NFRAG, 256, 0, stream>>>(band, bandcnt, bins4, vhl);
  walk_kernel<<<1, 64, 0, stream>>>(vhl, th);
  mask_pack_kernel<<<NB, TPB, 0, stream>>>(blurred, th, PKA);
  hmax_kernel<false><<<NBW, TPB, 0, stream>>>(PKA, PKB);  // dilate H
  vmax_kernel<<<NBW, TPB, 0, stream>>>(PKB, PKA);         // dilate V
  hmax_kernel<true><<<NBW, TPB, 0, stream>>>(PKA, PKB);   // erode H (complement in)
  vmax_kernel<<<NBW, TPB, 0, stream>>>(PKB, PKA);         // erode V
  unpack_kernel<<<NB, TPB, 0, stream>>>(PKA, out);        // out = ~bit
}